// Round 2
// baseline (536.788 us; speedup 1.0000x reference)
//
#include <hip/hip_runtime.h>
#include <stdint.h>

// out[M,N] = x[M,K] @ w_eff[N,K]^T + bias[N]
#define M_DIM 8192
#define N_DIM 4096
#define K_DIM 4096

#define BM 256
#define BN 256
#define BK 64
#define NT (K_DIM / BK)   // 64 K-tiles

typedef float v4f __attribute__((ext_vector_type(4)));
typedef __bf16 v8bf __attribute__((ext_vector_type(8)));

typedef __attribute__((address_space(3))) uint32_t lds_u32_t;
typedef const __attribute__((address_space(1))) uint32_t glb_u32_t;

__device__ inline uint16_t f2bf(float f) {
    union { float f; uint32_t u; } v; v.f = f;
    uint32_t r = v.u + 0x7fffu + ((v.u >> 16) & 1u);   // RNE
    return (uint16_t)(r >> 16);
}

// ---------------- kernel 1: x fp32 -> bf16 (unit-stride, grid-stride) ----------------
__global__ __launch_bounds__(256) void cvt_x(const float* __restrict__ x,
                                             uint16_t* __restrict__ xb,
                                             long long n4) {
    long long stride = (long long)gridDim.x * 256;
    for (long long i = (long long)blockIdx.x * 256 + threadIdx.x; i < n4; i += stride) {
        float4 a = ((const float4*)x)[i];
        union { uint16_t h[4]; uint2 u; } o;
        o.h[0] = f2bf(a.x); o.h[1] = f2bf(a.y); o.h[2] = f2bf(a.z); o.h[3] = f2bf(a.w);
        ((uint2*)xb)[i] = o.u;
    }
}

// ---------------- kernel 2: build w_eff (bf16, [N,K] = B^T layout) ----------------
__global__ __launch_bounds__(256) void make_weff(const float* __restrict__ w,
                                                 uint16_t* __restrict__ weff) {
    __shared__ double red[4];
    int row  = blockIdx.x;
    int tid  = threadIdx.x;
    int lane = tid & 63;
    int wid  = tid >> 6;

    const float* wr = w + (size_t)row * K_DIM;
    const float4* w4 = (const float4*)wr + tid * 4;
    float4 r0 = w4[0], r1 = w4[1], r2 = w4[2], r3 = w4[3];
    float v[16] = { r0.x, r0.y, r0.z, r0.w, r1.x, r1.y, r1.z, r1.w,
                    r2.x, r2.y, r2.z, r2.w, r3.x, r3.y, r3.z, r3.w };

    double s = 0.0;
#pragma unroll
    for (int j = 0; j < 16; j++) s += (double)v[j];
#pragma unroll
    for (int off = 32; off > 0; off >>= 1) s += __shfl_down(s, off);
    if (lane == 0) red[wid] = s;
    __syncthreads();
    double mu = (red[0] + red[1] + red[2] + red[3]) * (1.0 / 4096.0);
    __syncthreads();

    double sa = 0.0;
#pragma unroll
    for (int j = 0; j < 16; j++) sa += fabs((double)v[j] - mu);
#pragma unroll
    for (int off = 32; off > 0; off >>= 1) sa += __shfl_down(sa, off);
    if (lane == 0) red[wid] = sa;
    __syncthreads();
    double scale = (red[0] + red[1] + red[2] + red[3]) * (1.0 / 4096.0);

    float scf = (float)scale;
    union { uint16_t h[16]; uint4 u[2]; } o;
#pragma unroll
    for (int w2 = 0; w2 < 2; w2++) {
        int base = w2 * 8;
        int amax = 0;
        float mx = fabsf(v[base]);
#pragma unroll
        for (int j = 1; j < 8; j++) {
            float aj = fabsf(v[base + j]);
            if (aj > mx) { mx = aj; amax = j; }
        }
#pragma unroll
        for (int j = 0; j < 8; j++) {
            double wc = (double)v[base + j] - mu;
            float q = (wc > 0.0) ? scf : ((wc < 0.0) ? -scf : 0.0f);
            o.h[base + j] = f2bf((j == amax) ? v[base + j] : q);
        }
    }
    uint4* dst = (uint4*)(weff + (size_t)row * K_DIM + (size_t)tid * 16);
    dst[0] = o.u[0];
    dst[1] = o.u[1];
}

// ---------------- kernel 3: 256x256 tile, 8-phase pipelined bf16 MFMA GEMM ----------------
// 8 waves (2m x 4n), per-wave 128x64 out, mfma_f32_16x16x32_bf16, acc[8][4] f32x4.
// LDS (STATIC, 128 KB total): per operand [2 buf][2 k-half][256 rows][32 k] bf16
// (16 KB regions). Chunk swizzle slot = c ^ ((r>>1)&3) baked into the GLOBAL source
// address (global_load_lds dest must stay linear); fragment reads then hit all 8
// bank-quads per 8-lane group -> conflict-free ds_read_b128.
// Schedule: 4 phases/K-tile (mh,kh) = (0,0),(1,0),(1,1),(0,1); each phase issues one
// half-tile stage ~6 phases ahead; counted vmcnt(8) at q1/q3 only (never 0 in loop);
// raw s_barrier (no vmcnt drain); setprio(1) around the 16-MFMA cluster.

__device__ inline void async_cp16(const uint16_t* g, uint16_t* lds_uniform) {
    __builtin_amdgcn_global_load_lds((glb_u32_t*)g, (lds_u32_t*)lds_uniform, 16, 0, 0);
}

__device__ __forceinline__ void load4(v8bf (&d)[4], const uint16_t* base) {
#pragma unroll
    for (int i = 0; i < 4; ++i) d[i] = *(const v8bf*)(base + i * 512);
}

template<int MH>
__device__ __forceinline__ void mfma16(v4f (&acc)[8][4], const v8bf (&a)[4], const v8bf (&b)[4]) {
#pragma unroll
    for (int fm = 0; fm < 4; ++fm)
#pragma unroll
        for (int fn = 0; fn < 4; ++fn)
            acc[MH * 4 + fm][fn] =
                __builtin_amdgcn_mfma_f32_16x16x32_bf16(a[fm], b[fn], acc[MH * 4 + fm][fn], 0, 0, 0);
}

#define SB   __builtin_amdgcn_sched_barrier(0)
#define BAR  __builtin_amdgcn_s_barrier()
#define PRIO1 __builtin_amdgcn_s_setprio(1)
#define PRIO0 __builtin_amdgcn_s_setprio(0)
#define VMWAIT(N) asm volatile("s_waitcnt vmcnt(" #N ")" ::: "memory")
#define NOPW ((void)0)

// stage one (operand, k-half) half-tile of a K-tile: 256 rows x 32 k = 16 KB = 2 loads/thread
#define STG_A(BUFV, KHV, KOFF) do { \
    async_cp16(a_s0 + (KOFF) + (KHV) * 32, ldsA + ((BUFV) * 2 + (KHV)) * 8192 + wid * 1024);       \
    async_cp16(a_s1 + (KOFF) + (KHV) * 32, ldsA + ((BUFV) * 2 + (KHV)) * 8192 + wid * 1024 + 512); \
} while (0)
#define STG_B(BUFV, KHV, KOFF) do { \
    async_cp16(b_s0 + (KOFF) + (KHV) * 32, ldsB + ((BUFV) * 2 + (KHV)) * 8192 + wid * 1024);       \
    async_cp16(b_s1 + (KOFF) + (KHV) * 32, ldsB + ((BUFV) * 2 + (KHV)) * 8192 + wid * 1024 + 512); \
} while (0)

// One K-tile = 4 phases. Stages: q0:A-k1(t+1) q1:B-k1(t+1) q2:A-k0(t+2) q3:B-k0(t+2).
// Waits: q1 retires A-k1(t),B-k1(t) (needed q2); q3 retires A-k0(t+1),B-k0(t+1) (needed next q0).
#define TILE(BUFV, PF1, PF2, WQ1, WQ3, KN1, KN2)                               \
  {                                                                            \
    v8bf a_f[4], b0[4], b1[4];                                                 \
    /* q0: mh=0 kh=0 */                                                        \
    load4(a_f, rdA + ((BUFV) * 2 + 0) * 8192 + 0 * 2048);                      \
    load4(b0,  rdB + ((BUFV) * 2 + 0) * 8192);                                 \
    if (PF1) { STG_A(1 - (BUFV), 1, KN1); }                                    \
    SB; BAR; SB;                                                               \
    PRIO1; mfma16<0>(acc, a_f, b0); PRIO0;                                     \
    SB; BAR;                                                                   \
    /* q1: mh=1 kh=0 */                                                        \
    load4(a_f, rdA + ((BUFV) * 2 + 0) * 8192 + 1 * 2048);                      \
    if (PF1) { STG_B(1 - (BUFV), 1, KN1); }                                    \
    WQ1; SB; BAR; SB;                                                          \
    PRIO1; mfma16<1>(acc, a_f, b0); PRIO0;                                     \
    SB; BAR;                                                                   \
    /* q2: mh=1 kh=1 */                                                        \
    load4(a_f, rdA + ((BUFV) * 2 + 1) * 8192 + 1 * 2048);                      \
    load4(b1,  rdB + ((BUFV) * 2 + 1) * 8192);                                 \
    if (PF2) { STG_A((BUFV), 0, KN2); }                                        \
    SB; BAR; SB;                                                               \
    PRIO1; mfma16<1>(acc, a_f, b1); PRIO0;                                     \
    SB; BAR;                                                                   \
    /* q3: mh=0 kh=1 */                                                        \
    load4(a_f, rdA + ((BUFV) * 2 + 1) * 8192 + 0 * 2048);                      \
    if (PF2) { STG_B((BUFV), 0, KN2); }                                        \
    WQ3; SB; BAR; SB;                                                          \
    PRIO1; mfma16<0>(acc, a_f, b1); PRIO0;                                     \
    SB; BAR;                                                                   \
  }

__global__ __launch_bounds__(512, 2) void gemm_bt(const uint16_t* __restrict__ A,
                                                  const uint16_t* __restrict__ B,
                                                  const float* __restrict__ bias,
                                                  float* __restrict__ C) {
    // 128 KiB static LDS (gfx950 has 160 KiB/CU) — no dynamic-shared / attribute path
    __shared__ __attribute__((aligned(128))) uint16_t ldsA[4 * 8192];   // 64 KB
    __shared__ __attribute__((aligned(128))) uint16_t ldsB[4 * 8192];   // 64 KB

    int tid  = threadIdx.x;
    int lane = tid & 63;
    int wid  = tid >> 6;          // 0..7
    int wm   = wid >> 2;          // 0..1
    int wn   = wid & 3;           // 0..3

    // XCD-bijective swizzle: nwg = 512 (multiple of 8); each XCD gets 4 full N-rows of tiles
    int bid = blockIdx.x;
    int swz = (bid & 7) * 64 + (bid >> 3);
    long long bm = (long long)(swz >> 4) * BM;   // 0..31
    long long bn = (long long)(swz & 15) * BN;   // 0..15

    // staging geometry: one global_load_lds = 16 rows x 64 B (linear LDS dest);
    // source chunk pre-swizzled so LDS[r][slot] holds chunk slot^((r>>1)&3)
    int srow = lane >> 2;                               // 0..15
    int scs  = (lane & 3) ^ ((srow >> 1) & 3);          // source chunk (per-lane const)
    const uint16_t* a_s0 = A + (size_t)(bm + wid * 32 +  0 + srow) * K_DIM + scs * 8;
    const uint16_t* a_s1 = A + (size_t)(bm + wid * 32 + 16 + srow) * K_DIM + scs * 8;
    const uint16_t* b_s0 = B + (size_t)(bn + wid * 32 +  0 + srow) * K_DIM + scs * 8;
    const uint16_t* b_s1 = B + (size_t)(bn + wid * 32 + 16 + srow) * K_DIM + scs * 8;

    // fragment-read geometry: lane reads row rl=lane&15, chunk c=lane>>4; slot = c^((rl>>1)&3)
    int rl   = lane & 15;
    int aoff = rl * 32 + (((lane >> 4) ^ ((rl >> 1) & 3)) * 8);
    const uint16_t* rdA = ldsA + wm * 4096 + aoff;   // + region + mh*2048 + fm*512
    const uint16_t* rdB = ldsB + wn * 2048 + aoff;   // + region + fn*512

    v4f acc[8][4];
#pragma unroll
    for (int i = 0; i < 8; ++i)
#pragma unroll
        for (int j = 0; j < 4; ++j) acc[i][j] = (v4f)(0.0f);

    // prologue: tile0 all 4 halves + tile1 k0 halves (12 loads); retire tile0-k0 (oldest 4)
    STG_A(0, 0, 0); STG_B(0, 0, 0); STG_A(0, 1, 0); STG_B(0, 1, 0);
    STG_A(1, 0, 64); STG_B(1, 0, 64);
    VMWAIT(8); SB; BAR;

    // main: tiles 0..61 (buf alternates, compile-time), then exact-wait tail tiles 62, 63
#pragma clang loop unroll(disable)
    for (int it = 0; it < NT / 2 - 1; ++it) {
        int t2 = it * 2;
        TILE(0, 1, 1, VMWAIT(8), VMWAIT(8), (t2 + 1) * 64, (t2 + 2) * 64);
        TILE(1, 1, 1, VMWAIT(8), VMWAIT(8), (t2 + 2) * 64, (t2 + 3) * 64);
    }
    TILE(0, 1, 0, VMWAIT(8), VMWAIT(4), (NT - 1) * 64, 0);   // t = 62
    TILE(1, 0, 0, VMWAIT(0), NOPW, 0, 0);                    // t = 63

    // epilogue: 16x16 C/D layout col = lane&15, row = (lane>>4)*4 + reg
    int cl = lane & 15;
    int ch = lane >> 4;
#pragma unroll
    for (int fn = 0; fn < 4; ++fn) {
        int n = (int)bn + wn * 64 + fn * 16 + cl;
        float bj = bias[n];
#pragma unroll
        for (int m8 = 0; m8 < 8; ++m8) {
            size_t rbase = (size_t)(bm + wm * 128 + m8 * 16 + ch * 4) * N_DIM + n;
#pragma unroll
            for (int g = 0; g < 4; ++g)
                C[rbase + (size_t)g * N_DIM] = acc[m8][fn][g] + bj;
        }
    }
}

extern "C" void kernel_launch(void* const* d_in, const int* in_sizes, int n_in,
                              void* d_out, int out_size, void* d_ws, size_t ws_size,
                              hipStream_t stream) {
    const float* x    = (const float*)d_in[0];   // [4,2048,4096]
    const float* w    = (const float*)d_in[1];   // [4096,4096]
    const float* bias = (const float*)d_in[2];   // [4096]
    float* out = (float*)d_out;

    uint16_t* xb   = (uint16_t*)d_ws;
    uint16_t* weff = (uint16_t*)((char*)d_ws + (size_t)M_DIM * K_DIM * 2);

    long long n4 = (long long)M_DIM * K_DIM / 4;
    cvt_x<<<dim3(4096), dim3(256), 0, stream>>>(x, xb, n4);
    make_weff<<<dim3(N_DIM), dim3(256), 0, stream>>>(w, weff);
    gemm_bt<<<dim3(N_DIM / BN * (M_DIM / BM)), dim3(512), 0, stream>>>(xb, weff, bias, out);
}

// Round 3
// 525.507 us; speedup vs baseline: 1.0215x; 1.0215x over previous
//
#include <hip/hip_runtime.h>
#include <stdint.h>

// out[M,N] = x[M,K] @ w_eff[N,K]^T + bias[N]
#define M_DIM 8192
#define N_DIM 4096
#define K_DIM 4096

#define BM 256
#define BN 256
#define BK 64
#define NT (K_DIM / BK)   // 64 K-tiles

typedef float v4f __attribute__((ext_vector_type(4)));
typedef __bf16 v8bf __attribute__((ext_vector_type(8)));

typedef __attribute__((address_space(3))) uint32_t lds_u32_t;
typedef const __attribute__((address_space(1))) uint32_t glb_u32_t;

__device__ inline uint16_t f2bf(float f) {
    union { float f; uint32_t u; } v; v.f = f;
    uint32_t r = v.u + 0x7fffu + ((v.u >> 16) & 1u);   // RNE
    return (uint16_t)(r >> 16);
}

// ---------------- kernel 1: x fp32 -> bf16 (unit-stride, grid-stride) ----------------
__global__ __launch_bounds__(256) void cvt_x(const float* __restrict__ x,
                                             uint16_t* __restrict__ xb,
                                             long long n4) {
    long long stride = (long long)gridDim.x * 256;
    for (long long i = (long long)blockIdx.x * 256 + threadIdx.x; i < n4; i += stride) {
        float4 a = ((const float4*)x)[i];
        union { uint16_t h[4]; uint2 u; } o;
        o.h[0] = f2bf(a.x); o.h[1] = f2bf(a.y); o.h[2] = f2bf(a.z); o.h[3] = f2bf(a.w);
        ((uint2*)xb)[i] = o.u;
    }
}

// ---------------- kernel 2: build w_eff (bf16, [N,K] = B^T layout) ----------------
__global__ __launch_bounds__(256) void make_weff(const float* __restrict__ w,
                                                 uint16_t* __restrict__ weff) {
    __shared__ double red[4];
    int row  = blockIdx.x;
    int tid  = threadIdx.x;
    int lane = tid & 63;
    int wid  = tid >> 6;

    const float* wr = w + (size_t)row * K_DIM;
    const float4* w4 = (const float4*)wr + tid * 4;
    float4 r0 = w4[0], r1 = w4[1], r2 = w4[2], r3 = w4[3];
    float v[16] = { r0.x, r0.y, r0.z, r0.w, r1.x, r1.y, r1.z, r1.w,
                    r2.x, r2.y, r2.z, r2.w, r3.x, r3.y, r3.z, r3.w };

    double s = 0.0;
#pragma unroll
    for (int j = 0; j < 16; j++) s += (double)v[j];
#pragma unroll
    for (int off = 32; off > 0; off >>= 1) s += __shfl_down(s, off);
    if (lane == 0) red[wid] = s;
    __syncthreads();
    double mu = (red[0] + red[1] + red[2] + red[3]) * (1.0 / 4096.0);
    __syncthreads();

    double sa = 0.0;
#pragma unroll
    for (int j = 0; j < 16; j++) sa += fabs((double)v[j] - mu);
#pragma unroll
    for (int off = 32; off > 0; off >>= 1) sa += __shfl_down(sa, off);
    if (lane == 0) red[wid] = sa;
    __syncthreads();
    double scale = (red[0] + red[1] + red[2] + red[3]) * (1.0 / 4096.0);

    float scf = (float)scale;
    union { uint16_t h[16]; uint4 u[2]; } o;
#pragma unroll
    for (int w2 = 0; w2 < 2; w2++) {
        int base = w2 * 8;
        int amax = 0;
        float mx = fabsf(v[base]);
#pragma unroll
        for (int j = 1; j < 8; j++) {
            float aj = fabsf(v[base + j]);
            if (aj > mx) { mx = aj; amax = j; }
        }
#pragma unroll
        for (int j = 0; j < 8; j++) {
            double wc = (double)v[base + j] - mu;
            float q = (wc > 0.0) ? scf : ((wc < 0.0) ? -scf : 0.0f);
            o.h[base + j] = f2bf((j == amax) ? v[base + j] : q);
        }
    }
    uint4* dst = (uint4*)(weff + (size_t)row * K_DIM + (size_t)tid * 16);
    dst[0] = o.u[0];
    dst[1] = o.u[1];
}

// ---------------- kernel 3: 256x256 tile, pipelined bf16 MFMA GEMM ----------------
// 8 waves (2m x 4n), per-wave 128x64 out, mfma_f32_16x16x32_bf16, acc[8][4] f32x4.
// LDS (static, 128 KB): per operand [2 buf][2 k-half][256 rows][32 k] bf16 (16 KB regions).
// Chunk swizzle slot = c ^ ((r>>1)&3) baked into the GLOBAL source address; LDS dest
// stays linear for global_load_lds; fragment ds_read_b128 conflict-free (verified: 0).
// KEY CHANGE vs prev round: fragment register double-buffering (aX/aY, bX/bY) — each
// phase ISSUES the NEXT phase's ds_reads before its own MFMA cluster, so the LDS unit
// drains reads under the MFMA window instead of serializing read-window/MFMA-window.
// vmcnt(8) at q1/q3 only (never 0 in main loop); early reads of freshly-staged regions
// are issued strictly after that region's VMWAIT + barrier (cross-wave safe).

__device__ inline void async_cp16(const uint16_t* g, uint16_t* lds_uniform) {
    __builtin_amdgcn_global_load_lds((glb_u32_t*)g, (lds_u32_t*)lds_uniform, 16, 0, 0);
}

__device__ __forceinline__ void load4(v8bf (&d)[4], const uint16_t* base) {
#pragma unroll
    for (int i = 0; i < 4; ++i) d[i] = *(const v8bf*)(base + i * 512);
}

template<int MH>
__device__ __forceinline__ void mfma16(v4f (&acc)[8][4], const v8bf (&a)[4], const v8bf (&b)[4]) {
#pragma unroll
    for (int fm = 0; fm < 4; ++fm)
#pragma unroll
        for (int fn = 0; fn < 4; ++fn)
            acc[MH * 4 + fm][fn] =
                __builtin_amdgcn_mfma_f32_16x16x32_bf16(a[fm], b[fn], acc[MH * 4 + fm][fn], 0, 0, 0);
}

#define SB   __builtin_amdgcn_sched_barrier(0)
#define BAR  __builtin_amdgcn_s_barrier()
#define PRIO1 __builtin_amdgcn_s_setprio(1)
#define PRIO0 __builtin_amdgcn_s_setprio(0)
#define VMWAIT(N) asm volatile("s_waitcnt vmcnt(" #N ")" ::: "memory")
#define NOPW ((void)0)

// stage one (operand, k-half) half-tile of a K-tile: 256 rows x 32 k = 16 KB = 2 loads/thread
#define STG_A(BUFV, KHV, KOFF) do { \
    async_cp16(a_s0 + (KOFF) + (KHV) * 32, ldsA + ((BUFV) * 2 + (KHV)) * 8192 + wid * 1024);       \
    async_cp16(a_s1 + (KOFF) + (KHV) * 32, ldsA + ((BUFV) * 2 + (KHV)) * 8192 + wid * 1024 + 512); \
} while (0)
#define STG_B(BUFV, KHV, KOFF) do { \
    async_cp16(b_s0 + (KOFF) + (KHV) * 32, ldsB + ((BUFV) * 2 + (KHV)) * 8192 + wid * 1024);       \
    async_cp16(b_s1 + (KOFF) + (KHV) * 32, ldsB + ((BUFV) * 2 + (KHV)) * 8192 + wid * 1024 + 512); \
} while (0)

// One K-tile = 4 phases (mh,kh) = (0,0),(1,0),(1,1),(0,1).
// Frag sets: q0 uses aX,bX loads aY | q1 uses aY,bX loads aX,bY | q2 uses aX,bY loads aY
//            | q3 uses aY,bY loads next-tile aX,bX (from other buffer).
// Stages: q0:A-kh1(t+1) q1:B-kh1(t+1) q2:A-kh0(t+2) q3:B-kh0(t+2).
#define TILE(BUFV, PF1, PF2, WQ1, WQ3, KN1, KN2, EARLY3)                       \
  {                                                                            \
    /* q0: mh=0 kh=0 */                                                        \
    load4(aY, rdA + ((BUFV) * 2 + 0) * 8192 + 1 * 2048);   /* A mh1 kh0 */     \
    if (PF1) { STG_A(1 - (BUFV), 1, KN1); }                                    \
    SB; BAR; SB;                                                               \
    PRIO1; mfma16<0>(acc, aX, bX); PRIO0;                                      \
    SB; BAR; SB;                                                               \
    /* q1: mh=1 kh=0 */                                                        \
    if (PF1) { STG_B(1 - (BUFV), 1, KN1); }                                    \
    WQ1;                                                                       \
    SB; BAR; SB;                                                               \
    load4(aX, rdA + ((BUFV) * 2 + 1) * 8192 + 1 * 2048);   /* A mh1 kh1 */     \
    load4(bY, rdB + ((BUFV) * 2 + 1) * 8192);              /* B kh1 */         \
    SB;                                                                        \
    PRIO1; mfma16<1>(acc, aY, bX); PRIO0;                                      \
    SB; BAR; SB;                                                               \
    /* q2: mh=1 kh=1 */                                                        \
    load4(aY, rdA + ((BUFV) * 2 + 1) * 8192 + 0 * 2048);   /* A mh0 kh1 */     \
    if (PF2) { STG_A((BUFV), 0, KN2); }                                        \
    SB; BAR; SB;                                                               \
    PRIO1; mfma16<1>(acc, aX, bY); PRIO0;                                      \
    SB; BAR; SB;                                                               \
    /* q3: mh=0 kh=1 */                                                        \
    if (PF2) { STG_B((BUFV), 0, KN2); }                                        \
    WQ3;                                                                       \
    SB; BAR; SB;                                                               \
    if (EARLY3) {                                                              \
        load4(aX, rdA + ((1 - (BUFV)) * 2 + 0) * 8192 + 0 * 2048);             \
        load4(bX, rdB + ((1 - (BUFV)) * 2 + 0) * 8192);                        \
    }                                                                          \
    SB;                                                                        \
    PRIO1; mfma16<0>(acc, aY, bY); PRIO0;                                      \
    SB; BAR; SB;                                                               \
  }

__global__ __launch_bounds__(512, 2) void gemm_bt(const uint16_t* __restrict__ A,
                                                  const uint16_t* __restrict__ B,
                                                  const float* __restrict__ bias,
                                                  float* __restrict__ C) {
    __shared__ __attribute__((aligned(128))) uint16_t ldsA[4 * 8192];   // 64 KB
    __shared__ __attribute__((aligned(128))) uint16_t ldsB[4 * 8192];   // 64 KB

    int tid  = threadIdx.x;
    int lane = tid & 63;
    int wid  = tid >> 6;          // 0..7
    int wm   = wid >> 2;          // 0..1
    int wn   = wid & 3;           // 0..3

    // XCD-bijective swizzle: nwg = 512 (multiple of 8)
    int bid = blockIdx.x;
    int swz = (bid & 7) * 64 + (bid >> 3);
    long long bm = (long long)(swz >> 4) * BM;   // 0..31
    long long bn = (long long)(swz & 15) * BN;   // 0..15

    // staging geometry: one global_load_lds = 16 rows x 64 B (linear LDS dest);
    // source chunk pre-swizzled so LDS[r][slot] holds chunk slot^((r>>1)&3)
    int srow = lane >> 2;                               // 0..15
    int scs  = (lane & 3) ^ ((srow >> 1) & 3);          // source chunk (per-lane const)
    const uint16_t* a_s0 = A + (size_t)(bm + wid * 32 +  0 + srow) * K_DIM + scs * 8;
    const uint16_t* a_s1 = A + (size_t)(bm + wid * 32 + 16 + srow) * K_DIM + scs * 8;
    const uint16_t* b_s0 = B + (size_t)(bn + wid * 32 +  0 + srow) * K_DIM + scs * 8;
    const uint16_t* b_s1 = B + (size_t)(bn + wid * 32 + 16 + srow) * K_DIM + scs * 8;

    // fragment-read geometry: lane reads row rl=lane&15, chunk c=lane>>4; slot = c^((rl>>1)&3)
    int rl   = lane & 15;
    int aoff = rl * 32 + (((lane >> 4) ^ ((rl >> 1) & 3)) * 8);
    const uint16_t* rdA = ldsA + wm * 4096 + aoff;   // + region + mh*2048 + fm*512
    const uint16_t* rdB = ldsB + wn * 2048 + aoff;   // + region + fn*512

    v4f acc[8][4];
#pragma unroll
    for (int i = 0; i < 8; ++i)
#pragma unroll
        for (int j = 0; j < 4; ++j) acc[i][j] = (v4f)(0.0f);

    v8bf aX[4], aY[4], bX[4], bY[4];

    // prologue: tile0 all 4 halves + tile1 kh0 halves (12 loads); retire tile0-kh0 (oldest 4)
    STG_A(0, 0, 0); STG_B(0, 0, 0); STG_A(0, 1, 0); STG_B(0, 1, 0);
    STG_A(1, 0, 64); STG_B(1, 0, 64);
    VMWAIT(8); SB; BAR; SB;
    // preload q0 fragments: buf0 kh0 mh0 + B kh0
    load4(aX, rdA + 0 * 8192 + 0 * 2048);
    load4(bX, rdB + 0 * 8192);

    // main: tiles 0..61, then exact-wait tail tiles 62, 63
#pragma clang loop unroll(disable)
    for (int it = 0; it < NT / 2 - 1; ++it) {
        int t2 = it * 2;
        TILE(0, 1, 1, VMWAIT(8), VMWAIT(8), (t2 + 1) * 64, (t2 + 2) * 64, 1);
        TILE(1, 1, 1, VMWAIT(8), VMWAIT(8), (t2 + 2) * 64, (t2 + 3) * 64, 1);
    }
    TILE(0, 1, 0, VMWAIT(8), VMWAIT(4), (NT - 1) * 64, 0, 1);   // t = 62
    TILE(1, 0, 0, VMWAIT(0), NOPW, 0, 0, 0);                    // t = 63

    // epilogue: 16x16 C/D layout col = lane&15, row = (lane>>4)*4 + reg
    int cl = lane & 15;
    int ch = lane >> 4;
#pragma unroll
    for (int fn = 0; fn < 4; ++fn) {
        int n = (int)bn + wn * 64 + fn * 16 + cl;
        float bj = bias[n];
#pragma unroll
        for (int m8 = 0; m8 < 8; ++m8) {
            size_t rbase = (size_t)(bm + wm * 128 + m8 * 16 + ch * 4) * N_DIM + n;
#pragma unroll
            for (int g = 0; g < 4; ++g)
                C[rbase + (size_t)g * N_DIM] = acc[m8][fn][g] + bj;
        }
    }
}

extern "C" void kernel_launch(void* const* d_in, const int* in_sizes, int n_in,
                              void* d_out, int out_size, void* d_ws, size_t ws_size,
                              hipStream_t stream) {
    const float* x    = (const float*)d_in[0];   // [4,2048,4096]
    const float* w    = (const float*)d_in[1];   // [4096,4096]
    const float* bias = (const float*)d_in[2];   // [4096]
    float* out = (float*)d_out;

    uint16_t* xb   = (uint16_t*)d_ws;
    uint16_t* weff = (uint16_t*)((char*)d_ws + (size_t)M_DIM * K_DIM * 2);

    long long n4 = (long long)M_DIM * K_DIM / 4;
    cvt_x<<<dim3(4096), dim3(256), 0, stream>>>(x, xb, n4);
    make_weff<<<dim3(N_DIM), dim3(256), 0, stream>>>(w, weff);
    gemm_bt<<<dim3(N_DIM / BN * (M_DIM / BM)), dim3(512), 0, stream>>>(xb, weff, bias, out);
}

// Round 4
// 522.635 us; speedup vs baseline: 1.0271x; 1.0055x over previous
//
#include <hip/hip_runtime.h>
#include <stdint.h>

// out[M,N] = x[M,K] @ w_eff[N,K]^T + bias[N]
#define M_DIM 8192
#define N_DIM 4096
#define K_DIM 4096

#define BM 256
#define BN 256
#define BK 64
#define NT (K_DIM / BK)   // 64 K-tiles

typedef float v4f __attribute__((ext_vector_type(4)));
typedef __bf16 v8bf __attribute__((ext_vector_type(8)));

typedef __attribute__((address_space(3))) uint32_t lds_u32_t;
typedef const __attribute__((address_space(1))) uint32_t glb_u32_t;

__device__ inline uint16_t f2bf(float f) {
    union { float f; uint32_t u; } v; v.f = f;
    uint32_t r = v.u + 0x7fffu + ((v.u >> 16) & 1u);   // RNE
    return (uint16_t)(r >> 16);
}

// ---------------- kernel 1: x fp32 -> bf16 (unit-stride, grid-stride) ----------------
__global__ __launch_bounds__(256) void cvt_x(const float* __restrict__ x,
                                             uint16_t* __restrict__ xb,
                                             long long n4) {
    long long stride = (long long)gridDim.x * 256;
    for (long long i = (long long)blockIdx.x * 256 + threadIdx.x; i < n4; i += stride) {
        float4 a = ((const float4*)x)[i];
        union { uint16_t h[4]; uint2 u; } o;
        o.h[0] = f2bf(a.x); o.h[1] = f2bf(a.y); o.h[2] = f2bf(a.z); o.h[3] = f2bf(a.w);
        ((uint2*)xb)[i] = o.u;
    }
}

// ---------------- kernel 2: build w_eff (bf16, [N,K] = B^T layout) ----------------
__global__ __launch_bounds__(256) void make_weff(const float* __restrict__ w,
                                                 uint16_t* __restrict__ weff) {
    __shared__ double red[4];
    int row  = blockIdx.x;
    int tid  = threadIdx.x;
    int lane = tid & 63;
    int wid  = tid >> 6;

    const float* wr = w + (size_t)row * K_DIM;
    const float4* w4 = (const float4*)wr + tid * 4;
    float4 r0 = w4[0], r1 = w4[1], r2 = w4[2], r3 = w4[3];
    float v[16] = { r0.x, r0.y, r0.z, r0.w, r1.x, r1.y, r1.z, r1.w,
                    r2.x, r2.y, r2.z, r2.w, r3.x, r3.y, r3.z, r3.w };

    double s = 0.0;
#pragma unroll
    for (int j = 0; j < 16; j++) s += (double)v[j];
#pragma unroll
    for (int off = 32; off > 0; off >>= 1) s += __shfl_down(s, off);
    if (lane == 0) red[wid] = s;
    __syncthreads();
    double mu = (red[0] + red[1] + red[2] + red[3]) * (1.0 / 4096.0);
    __syncthreads();

    double sa = 0.0;
#pragma unroll
    for (int j = 0; j < 16; j++) sa += fabs((double)v[j] - mu);
#pragma unroll
    for (int off = 32; off > 0; off >>= 1) sa += __shfl_down(sa, off);
    if (lane == 0) red[wid] = sa;
    __syncthreads();
    double scale = (red[0] + red[1] + red[2] + red[3]) * (1.0 / 4096.0);

    float scf = (float)scale;
    union { uint16_t h[16]; uint4 u[2]; } o;
#pragma unroll
    for (int w2 = 0; w2 < 2; w2++) {
        int base = w2 * 8;
        int amax = 0;
        float mx = fabsf(v[base]);
#pragma unroll
        for (int j = 1; j < 8; j++) {
            float aj = fabsf(v[base + j]);
            if (aj > mx) { mx = aj; amax = j; }
        }
#pragma unroll
        for (int j = 0; j < 8; j++) {
            double wc = (double)v[base + j] - mu;
            float q = (wc > 0.0) ? scf : ((wc < 0.0) ? -scf : 0.0f);
            o.h[base + j] = f2bf((j == amax) ? v[base + j] : q);
        }
    }
    uint4* dst = (uint4*)(weff + (size_t)row * K_DIM + (size_t)tid * 16);
    dst[0] = o.u[0];
    dst[1] = o.u[1];
}

// ---------------- kernel 3: 256x256 tile, pipelined bf16 MFMA GEMM ----------------
// 8 waves (2m x 4n), per-wave 128x64 out, mfma_f32_16x16x32_bf16, acc[8][4] f32x4.
// LDS (static, 128 KB): per operand [2 buf][2 k-half][256 rows][32 k] bf16 (16 KB regions).
// Chunk swizzle slot = c ^ ((r>>1)&3) baked into the GLOBAL source address; LDS dest
// stays linear for global_load_lds; fragment ds_read_b128 conflict-free (verified: 0).
// Register double-buffered fragments (aX/aY, bX/bY); reads issued one phase early.
// KEY CHANGE vs prev round: REMOVED the sched_barrier(0) pinning (m141: SB-pinning
// costs ~40% by forcing the literal serial source order). The only retained SBs are
// after the three barriers that publish freshly-staged LDS regions (q1, q3, prologue):
// a wave's own vmcnt says nothing about OTHER waves' stages, and raw s_barrier is not
// an LLVM memory fence, so those reads must not hoist above the barrier. Everything
// else is left to the compiler scheduler (fine-grained lgkmcnt + ds_read/MFMA overlap).

__device__ inline void async_cp16(const uint16_t* g, uint16_t* lds_uniform) {
    __builtin_amdgcn_global_load_lds((glb_u32_t*)g, (lds_u32_t*)lds_uniform, 16, 0, 0);
}

__device__ __forceinline__ void load4(v8bf (&d)[4], const uint16_t* base) {
#pragma unroll
    for (int i = 0; i < 4; ++i) d[i] = *(const v8bf*)(base + i * 512);
}

template<int MH>
__device__ __forceinline__ void mfma16(v4f (&acc)[8][4], const v8bf (&a)[4], const v8bf (&b)[4]) {
#pragma unroll
    for (int fm = 0; fm < 4; ++fm)
#pragma unroll
        for (int fn = 0; fn < 4; ++fn)
            acc[MH * 4 + fm][fn] =
                __builtin_amdgcn_mfma_f32_16x16x32_bf16(a[fm], b[fn], acc[MH * 4 + fm][fn], 0, 0, 0);
}

#define SB   __builtin_amdgcn_sched_barrier(0)
#define BAR  __builtin_amdgcn_s_barrier()
#define PRIO1 __builtin_amdgcn_s_setprio(1)
#define PRIO0 __builtin_amdgcn_s_setprio(0)
#define VMWAIT(N) asm volatile("s_waitcnt vmcnt(" #N ")" ::: "memory")
#define NOPW ((void)0)

// stage one (operand, k-half) half-tile of a K-tile: 256 rows x 32 k = 16 KB = 2 loads/thread
#define STG_A(BUFV, KHV, KOFF) do { \
    async_cp16(a_s0 + (KOFF) + (KHV) * 32, ldsA + ((BUFV) * 2 + (KHV)) * 8192 + wid * 1024);       \
    async_cp16(a_s1 + (KOFF) + (KHV) * 32, ldsA + ((BUFV) * 2 + (KHV)) * 8192 + wid * 1024 + 512); \
} while (0)
#define STG_B(BUFV, KHV, KOFF) do { \
    async_cp16(b_s0 + (KOFF) + (KHV) * 32, ldsB + ((BUFV) * 2 + (KHV)) * 8192 + wid * 1024);       \
    async_cp16(b_s1 + (KOFF) + (KHV) * 32, ldsB + ((BUFV) * 2 + (KHV)) * 8192 + wid * 1024 + 512); \
} while (0)

// One K-tile = 4 phases (mh,kh) = (0,0),(1,0),(1,1),(0,1).
// Frag sets: q0 uses aX,bX loads aY | q1 uses aY,bX loads aX,bY | q2 uses aX,bY loads aY
//            | q3 uses aY,bY loads next-tile aX,bX (from other buffer).
// Stages: q0:A-kh1(t+1) q1:B-kh1(t+1) q2:A-kh0(t+2) q3:B-kh0(t+2).
// Waits: q1 retires A-kh1(t),B-kh1(t) (read right after); q3 retires A-kh0(t+1),
// B-kh0(t+1) (read right after, EARLY3).
#define TILE(BUFV, PF1, PF2, WQ1, WQ3, KN1, KN2, EARLY3)                       \
  {                                                                            \
    /* q0: mh=0 kh=0 */                                                        \
    load4(aY, rdA + ((BUFV) * 2 + 0) * 8192 + 1 * 2048);   /* A mh1 kh0 */     \
    if (PF1) { STG_A(1 - (BUFV), 1, KN1); }                                    \
    BAR;                                                                       \
    PRIO1; mfma16<0>(acc, aX, bX); PRIO0;                                      \
    BAR;                                                                       \
    /* q1: mh=1 kh=0 */                                                        \
    if (PF1) { STG_B(1 - (BUFV), 1, KN1); }                                    \
    WQ1;                                                                       \
    BAR; SB;                                                                   \
    load4(aX, rdA + ((BUFV) * 2 + 1) * 8192 + 1 * 2048);   /* A mh1 kh1 */     \
    load4(bY, rdB + ((BUFV) * 2 + 1) * 8192);              /* B kh1 */         \
    PRIO1; mfma16<1>(acc, aY, bX); PRIO0;                                      \
    BAR;                                                                       \
    /* q2: mh=1 kh=1 */                                                        \
    load4(aY, rdA + ((BUFV) * 2 + 1) * 8192 + 0 * 2048);   /* A mh0 kh1 */     \
    if (PF2) { STG_A((BUFV), 0, KN2); }                                        \
    BAR;                                                                       \
    PRIO1; mfma16<1>(acc, aX, bY); PRIO0;                                      \
    BAR;                                                                       \
    /* q3: mh=0 kh=1 */                                                        \
    if (PF2) { STG_B((BUFV), 0, KN2); }                                        \
    WQ3;                                                                       \
    BAR; SB;                                                                   \
    if (EARLY3) {                                                              \
        load4(aX, rdA + ((1 - (BUFV)) * 2 + 0) * 8192 + 0 * 2048);             \
        load4(bX, rdB + ((1 - (BUFV)) * 2 + 0) * 8192);                        \
    }                                                                          \
    PRIO1; mfma16<0>(acc, aY, bY); PRIO0;                                      \
    BAR;                                                                       \
  }

__global__ __launch_bounds__(512, 2) void gemm_bt(const uint16_t* __restrict__ A,
                                                  const uint16_t* __restrict__ B,
                                                  const float* __restrict__ bias,
                                                  float* __restrict__ C) {
    __shared__ __attribute__((aligned(128))) uint16_t ldsA[4 * 8192];   // 64 KB
    __shared__ __attribute__((aligned(128))) uint16_t ldsB[4 * 8192];   // 64 KB

    int tid  = threadIdx.x;
    int lane = tid & 63;
    int wid  = tid >> 6;          // 0..7
    int wm   = wid >> 2;          // 0..1
    int wn   = wid & 3;           // 0..3

    // XCD-bijective swizzle: nwg = 512 (multiple of 8)
    int bid = blockIdx.x;
    int swz = (bid & 7) * 64 + (bid >> 3);
    long long bm = (long long)(swz >> 4) * BM;   // 0..31
    long long bn = (long long)(swz & 15) * BN;   // 0..15

    // staging geometry: one global_load_lds = 16 rows x 64 B (linear LDS dest);
    // source chunk pre-swizzled so LDS[r][slot] holds chunk slot^((r>>1)&3)
    int srow = lane >> 2;                               // 0..15
    int scs  = (lane & 3) ^ ((srow >> 1) & 3);          // source chunk (per-lane const)
    const uint16_t* a_s0 = A + (size_t)(bm + wid * 32 +  0 + srow) * K_DIM + scs * 8;
    const uint16_t* a_s1 = A + (size_t)(bm + wid * 32 + 16 + srow) * K_DIM + scs * 8;
    const uint16_t* b_s0 = B + (size_t)(bn + wid * 32 +  0 + srow) * K_DIM + scs * 8;
    const uint16_t* b_s1 = B + (size_t)(bn + wid * 32 + 16 + srow) * K_DIM + scs * 8;

    // fragment-read geometry: lane reads row rl=lane&15, chunk c=lane>>4; slot = c^((rl>>1)&3)
    int rl   = lane & 15;
    int aoff = rl * 32 + (((lane >> 4) ^ ((rl >> 1) & 3)) * 8);
    const uint16_t* rdA = ldsA + wm * 4096 + aoff;   // + region + mh*2048 + fm*512
    const uint16_t* rdB = ldsB + wn * 2048 + aoff;   // + region + fn*512

    v4f acc[8][4];
#pragma unroll
    for (int i = 0; i < 8; ++i)
#pragma unroll
        for (int j = 0; j < 4; ++j) acc[i][j] = (v4f)(0.0f);

    v8bf aX[4], aY[4], bX[4], bY[4];

    // prologue: tile0 all 4 halves + tile1 kh0 halves (12 loads); retire tile0-kh0 (oldest 4)
    STG_A(0, 0, 0); STG_B(0, 0, 0); STG_A(0, 1, 0); STG_B(0, 1, 0);
    STG_A(1, 0, 64); STG_B(1, 0, 64);
    VMWAIT(8); BAR; SB;
    // preload q0 fragments: buf0 kh0 mh0 + B kh0
    load4(aX, rdA + 0 * 8192 + 0 * 2048);
    load4(bX, rdB + 0 * 8192);

    // main: tiles 0..61, then exact-wait tail tiles 62, 63
#pragma clang loop unroll(disable)
    for (int it = 0; it < NT / 2 - 1; ++it) {
        int t2 = it * 2;
        TILE(0, 1, 1, VMWAIT(8), VMWAIT(8), (t2 + 1) * 64, (t2 + 2) * 64, 1);
        TILE(1, 1, 1, VMWAIT(8), VMWAIT(8), (t2 + 2) * 64, (t2 + 3) * 64, 1);
    }
    TILE(0, 1, 0, VMWAIT(8), VMWAIT(4), (NT - 1) * 64, 0, 1);   // t = 62
    TILE(1, 0, 0, VMWAIT(0), NOPW, 0, 0, 0);                    // t = 63

    // epilogue: 16x16 C/D layout col = lane&15, row = (lane>>4)*4 + reg
    int cl = lane & 15;
    int ch = lane >> 4;
#pragma unroll
    for (int fn = 0; fn < 4; ++fn) {
        int n = (int)bn + wn * 64 + fn * 16 + cl;
        float bj = bias[n];
#pragma unroll
        for (int m8 = 0; m8 < 8; ++m8) {
            size_t rbase = (size_t)(bm + wm * 128 + m8 * 16 + ch * 4) * N_DIM + n;
#pragma unroll
            for (int g = 0; g < 4; ++g)
                C[rbase + (size_t)g * N_DIM] = acc[m8][fn][g] + bj;
        }
    }
}

extern "C" void kernel_launch(void* const* d_in, const int* in_sizes, int n_in,
                              void* d_out, int out_size, void* d_ws, size_t ws_size,
                              hipStream_t stream) {
    const float* x    = (const float*)d_in[0];   // [4,2048,4096]
    const float* w    = (const float*)d_in[1];   // [4096,4096]
    const float* bias = (const float*)d_in[2];   // [4096]
    float* out = (float*)d_out;

    uint16_t* xb   = (uint16_t*)d_ws;
    uint16_t* weff = (uint16_t*)((char*)d_ws + (size_t)M_DIM * K_DIM * 2);

    long long n4 = (long long)M_DIM * K_DIM / 4;
    cvt_x<<<dim3(4096), dim3(256), 0, stream>>>(x, xb, n4);
    make_weff<<<dim3(N_DIM), dim3(256), 0, stream>>>(w, weff);
    gemm_bt<<<dim3(N_DIM / BN * (M_DIM / BM)), dim3(512), 0, stream>>>(xb, weff, bias, out);
}